// Round 3
// baseline (163.998 us; speedup 1.0000x reference)
//
#include <hip/hip_runtime.h>
#include <hip/hip_bf16.h>

// Problem constants (from setup_inputs)
#define B_ROWS 4096
#define D_IN   512
#define D_PCA  100
#define NPAD_W 112            // W rows padded to 7*16
#define KP     128            // padded K (100 data + 4 aug + 24 zero)
#define N_REF  50000
#define N_PAD  50048          // 1564 * 32
#define NCH    1564           // chunks of 32 X-rows
#define NSPLIT 64
#define CH_BYTES 8192         // 32 rows * 256 B
#define XPREP_BLKS 3128       // N_PAD/16
#define WPREP_BLKS 56         // 112*512/1024

typedef __attribute__((ext_vector_type(8))) short s8v;   // 8 x bf16 (4 VGPR)
typedef __attribute__((ext_vector_type(4))) short s4v;   // 4 x bf16
typedef __attribute__((ext_vector_type(4))) float f4v;   // 4 x f32

__device__ __forceinline__ float fast_exp2(float x) {
#if __has_builtin(__builtin_amdgcn_exp2f)
  return __builtin_amdgcn_exp2f(x);
#else
  float r; asm("v_exp_f32 %0, %1" : "=v"(r) : "v"(x)); return r;
#endif
}

__device__ __forceinline__ short bf16bits(float v) {
  __hip_bfloat16 b = __float2bfloat16(v);
  return *reinterpret_cast<short*>(&b);
}

// ---------------- Kernel B: X_ref augmentation + W->bf16 conversion ----------------
// X'[n] = [bf16(X_0..99), 1, 1, hi(-0.5|X|^2), lo(-0.5|X|^2), 0...0]
// pad rows (n >= N): all zero except col102 = -30000 (=> logit -> -inf)
// blocks >= XPREP_BLKS convert W[100][512] f32 -> Wb[112][512] bf16 (pad rows 0)
__global__ __launch_bounds__(256) void xprep_kernel(
    const float* __restrict__ X, const float* __restrict__ W,
    __hip_bfloat16* __restrict__ Xb, __hip_bfloat16* __restrict__ Wb) {
  const int t = threadIdx.x;
  if (blockIdx.x >= XPREP_BLKS) {                    // W conversion path
    const int i4 = (blockIdx.x - XPREP_BLKS) * 256 + t;  // float4 index in [112][512]
    const int row = i4 >> 7, col = (i4 & 127) * 4;
    float4 v = {0.f, 0.f, 0.f, 0.f};
    if (row < D_PCA) v = *(const float4*)(W + (size_t)row * 512 + col);
    s4v o; o[0] = bf16bits(v.x); o[1] = bf16bits(v.y);
    o[2] = bf16bits(v.z); o[3] = bf16bits(v.w);
    *(s4v*)(Wb + (size_t)row * 512 + col) = o;
    return;
  }
  __shared__ float xl[1600];
  __shared__ float bhi[16], blo[16];
  const long n0 = (long)blockIdx.x * 16;
  if (n0 < N_REF) {
    const float4* src = (const float4*)(X + n0 * D_PCA);
    for (int i = t; i < 400; i += 256) ((float4*)xl)[i] = src[i];
    __syncthreads();
    if (t < 16) {
      float s = 0.f;
      for (int c = 0; c < D_PCA; ++c) { float v = xl[t * 100 + c]; s = fmaf(v, v, s); }
      float v = -0.5f * s;
      float hi = __bfloat162float(__float2bfloat16(v));
      bhi[t] = hi; blo[t] = v - hi;
    }
    __syncthreads();
    for (int o = t; o < 2048; o += 256) {
      const int r = o >> 7, c = o & 127;
      float val;
      if (c < D_PCA) val = xl[r * 100 + c];
      else if (c == 100 || c == 101) val = 1.0f;
      else if (c == 102) val = bhi[r];
      else if (c == 103) val = blo[r];
      else val = 0.0f;
      Xb[(n0 + r) * KP + c] = __float2bfloat16(val);
    }
  } else {
    for (int o = t; o < 2048; o += 256) {
      const int r = o >> 7, c = o & 127;
      Xb[(n0 + r) * KP + c] = __float2bfloat16(c == 102 ? -30000.0f : 0.0f);
    }
  }
}

// ---------------- Kernel A: PCA via MFMA (split-K) + augmentation ----------------
// grid 256 blocks: block computes 16 h-rows; 4 waves split K=512 into 128 each.
__global__ __launch_bounds__(256) void pca2_kernel(
    const float* __restrict__ x, const __hip_bfloat16* __restrict__ Wb,
    const float* __restrict__ bvec, __hip_bfloat16* __restrict__ Hb) {
  __shared__ float part[4][16][113];                 // +1 pad on inner dim
  const int t = threadIdx.x;
  const int lane = t & 63, w = t >> 6;
  const int g = lane >> 4, l15 = lane & 15;
  const int rbase = blockIdx.x * 16;

  f4v acc[7];
#pragma unroll
  for (int nf = 0; nf < 7; ++nf) acc[nf] = f4v{0.f, 0.f, 0.f, 0.f};

#pragma unroll
  for (int ks = 0; ks < 4; ++ks) {
    const int k0 = w * 128 + ks * 32 + g * 8;        // wave-private K slice
    const float* xp = x + (size_t)(rbase + l15) * 512 + k0;
    float4 xa = *(const float4*)xp;
    float4 xb = *(const float4*)(xp + 4);
    s8v af;
    af[0] = bf16bits(xa.x); af[1] = bf16bits(xa.y);
    af[2] = bf16bits(xa.z); af[3] = bf16bits(xa.w);
    af[4] = bf16bits(xb.x); af[5] = bf16bits(xb.y);
    af[6] = bf16bits(xb.z); af[7] = bf16bits(xb.w);
#pragma unroll
    for (int nf = 0; nf < 7; ++nf) {
      s8v bf = *(const s8v*)(Wb + (size_t)(nf * 16 + l15) * 512 + k0);
      acc[nf] = __builtin_amdgcn_mfma_f32_16x16x32_bf16(af, bf, acc[nf], 0, 0, 0);
    }
  }
  // stash wave partials: C layout row=(g*4+reg) (x-row), col=(nf*16+l15) (h-col)
#pragma unroll
  for (int nf = 0; nf < 7; ++nf)
#pragma unroll
    for (int reg = 0; reg < 4; ++reg)
      part[w][g * 4 + reg][nf * 16 + l15] = acc[nf][reg];
  __syncthreads();

  // finish: thread t -> row=t>>4 (16 rows), cols cb..cb+6 (16 threads x 7 = 112)
  const int row = t >> 4, cb = (t & 15) * 7;
  float h[7]; float ps = 0.f;
#pragma unroll
  for (int j = 0; j < 7; ++j) {
    const int c = cb + j;
    float v = part[0][row][c] + part[1][row][c] + part[2][row][c] + part[3][row][c];
    v += (c < D_PCA) ? bvec[c] : 0.f;
    h[j] = v; ps = fmaf(v, v, ps);
  }
  ps += __shfl_xor(ps, 1, 64);
  ps += __shfl_xor(ps, 2, 64);
  ps += __shfl_xor(ps, 4, 64);
  ps += __shfl_xor(ps, 8, 64);
  const float vneg = -0.5f * ps;
  const float hi = __bfloat162float(__float2bfloat16(vneg));
  const float lo = vneg - hi;
  __hip_bfloat16* hrow = Hb + (size_t)(rbase + row) * KP;
#pragma unroll
  for (int j = 0; j < 7; ++j) {
    const int c = cb + j;
    float val = (c < D_PCA) ? h[j]
              : (c == 100) ? hi
              : (c == 101) ? lo
              : (c == 102 || c == 103) ? 1.0f : 0.0f;
    hrow[c] = __float2bfloat16(val);
  }
  if ((t & 15) == 15) {                              // cols 112..127 zeros
    s8v z = {0, 0, 0, 0, 0, 0, 0, 0};
    *(s8v*)(hrow + 112) = z;
    *(s8v*)(hrow + 120) = z;
  }
}

// ---------------- Kernel C: fused distance-matmul + exp-sum ----------------
// stage one 32-row X' chunk (8 KB): linear LDS dest, pre-swizzled global src
__device__ __forceinline__ void stage_tile(char* lds, const char* gtile, int t) {
#pragma unroll
  for (int i = 0; i < 2; ++i) {
    const int L = i * 4096 + t * 16;                 // linear LDS dest (lane-contiguous)
    const int G = L ^ (((L >> 8) & 7) << 4);         // pre-swizzled global source (involution)
    __builtin_amdgcn_global_load_lds(
        (const __attribute__((address_space(1))) void*)(gtile + G),
        (__attribute__((address_space(3))) void*)(lds + L), 16, 0, 0);
  }
}

__global__ __launch_bounds__(256, 8) void kde_kernel(
    const __hip_bfloat16* __restrict__ Hb, const char* __restrict__ Xbc,
    const float* __restrict__ bwp, float* __restrict__ spart) {
  __shared__ char ldsx[2][CH_BYTES];                 // double-buffered X' chunk [32][256B]
  const int t = threadIdx.x;
  const int lane = t & 63, w = t >> 6;
  const int g = lane >> 4, l15 = lane & 15;
  const int rb = blockIdx.x / NSPLIT, sp = blockIdx.x % NSPLIT;
  const int c0 = (sp * NCH) / NSPLIT;
  const int c1 = ((sp + 1) * NCH) / NSPLIT;
  const float bw = bwp[0];
  const float k1 = 1.4426950408889634f / (bw * bw);  // log2(e)/bw^2
  const int rowbase = rb * 128 + w * 32;             // 4 waves x 32 rows = 128 rows/block

  // A fragments: h' rows in registers for the whole kernel (2 rf x 4 ks = 32 VGPR)
  s8v a[2][4];
#pragma unroll
  for (int rf = 0; rf < 2; ++rf)
#pragma unroll
    for (int ks = 0; ks < 4; ++ks) {
      const int row = rowbase + rf * 16 + l15;
      a[rf][ks] = *(const s8v*)(Hb + (size_t)row * KP + ks * 32 + g * 8);
    }

  float sacc[8];                                     // per-lane partial sums (rf x reg)
#pragma unroll
  for (int i = 0; i < 8; ++i) sacc[i] = 0.0f;

  stage_tile(ldsx[0], Xbc + (size_t)c0 * CH_BYTES, t);
  __syncthreads();

  const f4v zero4 = {0.0f, 0.0f, 0.0f, 0.0f};
  for (int ch = c0; ch < c1; ++ch) {
    const int cur = (ch - c0) & 1;
    if (ch + 1 < c1) stage_tile(ldsx[cur ^ 1], Xbc + (size_t)(ch + 1) * CH_BYTES, t);
    const char* lx = ldsx[cur];
#pragma unroll
    for (int cf = 0; cf < 2; ++cf) {                 // 2 col-frags of 16 X-rows
      const int nl = cf * 16 + l15;                  // local X row in chunk
      const int sw = (nl & 7) << 4;                  // read-side XOR swizzle
      const int qb = nl * 256 + g * 16;
      s8v b0 = *(const s8v*)(lx + ((qb) ^ sw));
      s8v b1 = *(const s8v*)(lx + ((qb + 64) ^ sw));
      s8v b2 = *(const s8v*)(lx + ((qb + 128) ^ sw));
      s8v b3 = *(const s8v*)(lx + ((qb + 192) ^ sw));
      __builtin_amdgcn_s_setprio(1);
      f4v acc0 = __builtin_amdgcn_mfma_f32_16x16x32_bf16(a[0][0], b0, zero4, 0, 0, 0);
      acc0 = __builtin_amdgcn_mfma_f32_16x16x32_bf16(a[0][1], b1, acc0, 0, 0, 0);
      acc0 = __builtin_amdgcn_mfma_f32_16x16x32_bf16(a[0][2], b2, acc0, 0, 0, 0);
      acc0 = __builtin_amdgcn_mfma_f32_16x16x32_bf16(a[0][3], b3, acc0, 0, 0, 0);
      f4v acc1 = __builtin_amdgcn_mfma_f32_16x16x32_bf16(a[1][0], b0, zero4, 0, 0, 0);
      acc1 = __builtin_amdgcn_mfma_f32_16x16x32_bf16(a[1][1], b1, acc1, 0, 0, 0);
      acc1 = __builtin_amdgcn_mfma_f32_16x16x32_bf16(a[1][2], b2, acc1, 0, 0, 0);
      acc1 = __builtin_amdgcn_mfma_f32_16x16x32_bf16(a[1][3], b3, acc1, 0, 0, 0);
      __builtin_amdgcn_s_setprio(0);
      // epilogue: acc = -sqdist/2 (aug trick); s += exp2(acc*log2e/bw^2 + 144.27)
#pragma unroll
      for (int reg = 0; reg < 4; ++reg)
        sacc[reg] += fast_exp2(fmaf(acc0[reg], k1, 144.26950408889634f));
#pragma unroll
      for (int reg = 0; reg < 4; ++reg)
        sacc[4 + reg] += fast_exp2(fmaf(acc1[reg], k1, 144.26950408889634f));
    }
    __syncthreads();  // drains prefetch vmcnt + guards LDS reuse (single barrier/chunk)
  }

  // butterfly-reduce the 16 column-lanes; rows live at lane-group g, regs rf x reg
#pragma unroll
  for (int i = 0; i < 8; ++i) {
    float v = sacc[i];
    v += __shfl_xor(v, 1, 64);
    v += __shfl_xor(v, 2, 64);
    v += __shfl_xor(v, 4, 64);
    v += __shfl_xor(v, 8, 64);
    sacc[i] = v;
  }
  if (l15 == 0) {
#pragma unroll
    for (int rf = 0; rf < 2; ++rf)
#pragma unroll
      for (int reg = 0; reg < 4; ++reg) {
        const int row = rowbase + rf * 16 + g * 4 + reg;
        spart[sp * B_ROWS + row] = sacc[rf * 4 + reg];
      }
  }
}

// ---------------- Kernel D: combine partials ----------------
__global__ __launch_bounds__(256) void combine_kernel(
    const float* __restrict__ spart, const float* __restrict__ bwp,
    float* __restrict__ out) {
  const int b = blockIdx.x * 256 + threadIdx.x;
  if (b >= B_ROWS) return;
  float s = 0.f;
#pragma unroll
  for (int sp = 0; sp < NSPLIT; ++sp) s += spart[sp * B_ROWS + b];
  const float bw = bwp[0];
  const float LOG2PI = 1.8378770664093453f;
  const float coeff = -logf((float)N_REF) - 0.5f * LOG2PI * (float)D_PCA
                      - logf(bw) * (float)D_PCA;
  out[b] = logf(s) - 100.0f + coeff;   // undo the +100 exp shift
}

// ---------------- Launch ----------------
extern "C" void kernel_launch(void* const* d_in, const int* in_sizes, int n_in,
                              void* d_out, int out_size, void* d_ws, size_t ws_size,
                              hipStream_t stream) {
  const float* x     = (const float*)d_in[0];   // [4096,512]
  const float* W     = (const float*)d_in[1];   // [100,512]
  const float* bvec  = (const float*)d_in[2];   // [100]
  const float* X     = (const float*)d_in[3];   // [50000,100]
  const float* bwp   = (const float*)d_in[4];   // scalar
  float* out = (float*)d_out;

  char* ws = (char*)d_ws;
  __hip_bfloat16* Hb = (__hip_bfloat16*)ws;                       // 4096*128*2   = 1 MiB
  __hip_bfloat16* Xb = (__hip_bfloat16*)(ws + 1048576);           // 50048*128*2  = 12.22 MiB
  __hip_bfloat16* Wb = (__hip_bfloat16*)(ws + 13860864);          // 112*512*2    = 112 KiB
  float* spart       = (float*)(ws + 13975552);                   // 64*4096*4    = 1 MiB

  xprep_kernel<<<dim3(XPREP_BLKS + WPREP_BLKS), dim3(256), 0, stream>>>(X, W, Xb, Wb);
  pca2_kernel<<<dim3(B_ROWS / 16), dim3(256), 0, stream>>>(x, Wb, bvec, Hb);
  kde_kernel<<<dim3((B_ROWS / 128) * NSPLIT), dim3(256), 0, stream>>>(
      Hb, (const char*)Xb, bwp, spart);
  combine_kernel<<<dim3(B_ROWS / 256), dim3(256), 0, stream>>>(spart, bwp, out);
}

// Round 4
// 82.747 us; speedup vs baseline: 1.9819x; 1.9819x over previous
//
#include <hip/hip_runtime.h>
#include <hip/hip_bf16.h>

// Problem constants (from setup_inputs)
#define B_ROWS 4096
#define D_IN   512
#define D_PCA  100
#define NPAD_W 112            // W rows padded to 7*16
#define KP     128            // padded K (100 data + 4 aug + 24 zero)
#define N_REF  50000
#define N_PAD  50048          // 782 * 64
#define NCH    782            // chunks of 64 X-rows
#define NSPLIT 40             // grid 32*40=1280 = 5 blocks/CU; 40%8==0 keeps split on 1 XCD
#define CH_BYTES 16384        // 64 rows * 256 B
#define XPREP_BLKS 3128       // N_PAD/16
#define WPREP_BLKS 56         // 112*512/1024

typedef __attribute__((ext_vector_type(8))) short s8v;   // 8 x bf16 (4 VGPR)
typedef __attribute__((ext_vector_type(4))) short s4v;   // 4 x bf16
typedef __attribute__((ext_vector_type(4))) float f4v;   // 4 x f32

__device__ __forceinline__ float fast_exp2(float x) {
#if __has_builtin(__builtin_amdgcn_exp2f)
  return __builtin_amdgcn_exp2f(x);
#else
  float r; asm("v_exp_f32 %0, %1" : "=v"(r) : "v"(x)); return r;
#endif
}

__device__ __forceinline__ short bf16bits(float v) {
  __hip_bfloat16 b = __float2bfloat16(v);
  return *reinterpret_cast<short*>(&b);
}

// ---------------- Kernel B: X_ref augmentation + W->bf16 conversion ----------------
// X'[n] = [bf16(X_0..99), 1, 1, hi(-0.5|X|^2), lo(-0.5|X|^2), 0...0]
// pad rows (n >= N): all zero except col102 = -30000 (=> logit -> -inf)
// blocks >= XPREP_BLKS convert W[100][512] f32 -> Wb[112][512] bf16 (pad rows 0)
__global__ __launch_bounds__(256) void xprep_kernel(
    const float* __restrict__ X, const float* __restrict__ W,
    __hip_bfloat16* __restrict__ Xb, __hip_bfloat16* __restrict__ Wb) {
  const int t = threadIdx.x;
  if (blockIdx.x >= XPREP_BLKS) {                    // W conversion path
    const int i4 = (blockIdx.x - XPREP_BLKS) * 256 + t;  // float4 index in [112][512]
    const int row = i4 >> 7, col = (i4 & 127) * 4;
    float4 v = {0.f, 0.f, 0.f, 0.f};
    if (row < D_PCA) v = *(const float4*)(W + (size_t)row * 512 + col);
    s4v o; o[0] = bf16bits(v.x); o[1] = bf16bits(v.y);
    o[2] = bf16bits(v.z); o[3] = bf16bits(v.w);
    *(s4v*)(Wb + (size_t)row * 512 + col) = o;
    return;
  }
  __shared__ float xl[1600];
  __shared__ float bhi[16], blo[16];
  const long n0 = (long)blockIdx.x * 16;
  if (n0 < N_REF) {
    const float4* src = (const float4*)(X + n0 * D_PCA);
    for (int i = t; i < 400; i += 256) ((float4*)xl)[i] = src[i];
    __syncthreads();
    if (t < 16) {
      float s = 0.f;
      for (int c = 0; c < D_PCA; ++c) { float v = xl[t * 100 + c]; s = fmaf(v, v, s); }
      float v = -0.5f * s;
      float hi = __bfloat162float(__float2bfloat16(v));
      bhi[t] = hi; blo[t] = v - hi;
    }
    __syncthreads();
    for (int o = t; o < 2048; o += 256) {
      const int r = o >> 7, c = o & 127;
      float val;
      if (c < D_PCA) val = xl[r * 100 + c];
      else if (c == 100 || c == 101) val = 1.0f;
      else if (c == 102) val = bhi[r];
      else if (c == 103) val = blo[r];
      else val = 0.0f;
      Xb[(n0 + r) * KP + c] = __float2bfloat16(val);
    }
  } else {
    for (int o = t; o < 2048; o += 256) {
      const int r = o >> 7, c = o & 127;
      Xb[(n0 + r) * KP + c] = __float2bfloat16(c == 102 ? -30000.0f : 0.0f);
    }
  }
}

// ---------------- Kernel A: PCA via MFMA (split-K) + augmentation ----------------
// grid 256 blocks: block computes 16 h-rows; 4 waves split K=512 into 128 each.
__global__ __launch_bounds__(256) void pca2_kernel(
    const float* __restrict__ x, const __hip_bfloat16* __restrict__ Wb,
    const float* __restrict__ bvec, __hip_bfloat16* __restrict__ Hb) {
  __shared__ float part[4][16][113];                 // +1 pad on inner dim
  const int t = threadIdx.x;
  const int lane = t & 63, w = t >> 6;
  const int g = lane >> 4, l15 = lane & 15;
  const int rbase = blockIdx.x * 16;

  f4v acc[7];
#pragma unroll
  for (int nf = 0; nf < 7; ++nf) acc[nf] = f4v{0.f, 0.f, 0.f, 0.f};

#pragma unroll
  for (int ks = 0; ks < 4; ++ks) {
    const int k0 = w * 128 + ks * 32 + g * 8;        // wave-private K slice
    const float* xp = x + (size_t)(rbase + l15) * 512 + k0;
    float4 xa = *(const float4*)xp;
    float4 xb = *(const float4*)(xp + 4);
    s8v af;
    af[0] = bf16bits(xa.x); af[1] = bf16bits(xa.y);
    af[2] = bf16bits(xa.z); af[3] = bf16bits(xa.w);
    af[4] = bf16bits(xb.x); af[5] = bf16bits(xb.y);
    af[6] = bf16bits(xb.z); af[7] = bf16bits(xb.w);
#pragma unroll
    for (int nf = 0; nf < 7; ++nf) {
      s8v bf = *(const s8v*)(Wb + (size_t)(nf * 16 + l15) * 512 + k0);
      acc[nf] = __builtin_amdgcn_mfma_f32_16x16x32_bf16(af, bf, acc[nf], 0, 0, 0);
    }
  }
  // stash wave partials: C layout row=(g*4+reg) (x-row), col=(nf*16+l15) (h-col)
#pragma unroll
  for (int nf = 0; nf < 7; ++nf)
#pragma unroll
    for (int reg = 0; reg < 4; ++reg)
      part[w][g * 4 + reg][nf * 16 + l15] = acc[nf][reg];
  __syncthreads();

  // finish: thread t -> row=t>>4 (16 rows), cols cb..cb+6 (16 threads x 7 = 112)
  const int row = t >> 4, cb = (t & 15) * 7;
  float h[7]; float ps = 0.f;
#pragma unroll
  for (int j = 0; j < 7; ++j) {
    const int c = cb + j;
    float v = part[0][row][c] + part[1][row][c] + part[2][row][c] + part[3][row][c];
    v += (c < D_PCA) ? bvec[c] : 0.f;
    h[j] = v; ps = fmaf(v, v, ps);
  }
  ps += __shfl_xor(ps, 1, 64);
  ps += __shfl_xor(ps, 2, 64);
  ps += __shfl_xor(ps, 4, 64);
  ps += __shfl_xor(ps, 8, 64);
  const float vneg = -0.5f * ps;
  const float hi = __bfloat162float(__float2bfloat16(vneg));
  const float lo = vneg - hi;
  __hip_bfloat16* hrow = Hb + (size_t)(rbase + row) * KP;
#pragma unroll
  for (int j = 0; j < 7; ++j) {
    const int c = cb + j;
    float val = (c < D_PCA) ? h[j]
              : (c == 100) ? hi
              : (c == 101) ? lo
              : (c == 102 || c == 103) ? 1.0f : 0.0f;
    hrow[c] = __float2bfloat16(val);
  }
  if ((t & 15) == 15) {                              // cols 112..127 zeros
    s8v z = {0, 0, 0, 0, 0, 0, 0, 0};
    *(s8v*)(hrow + 112) = z;
    *(s8v*)(hrow + 120) = z;
  }
}

// ---------------- Kernel C: fused distance-matmul + exp-sum ----------------
// stage one 64-row X' chunk (16 KB): linear LDS dest, pre-swizzled global src
// 4 global_load_lds (vmcnt ops) per thread per call
__device__ __forceinline__ void stage_tile(char* lds, const char* gtile, int t) {
#pragma unroll
  for (int i = 0; i < 4; ++i) {
    const int L = i * 4096 + t * 16;                 // linear LDS dest (lane-contiguous)
    const int G = L ^ (((L >> 8) & 7) << 4);         // pre-swizzled global source (involution)
    __builtin_amdgcn_global_load_lds(
        (const __attribute__((address_space(1))) void*)(gtile + G),
        (__attribute__((address_space(3))) void*)(lds + L), 16, 0, 0);
  }
}

__global__ __launch_bounds__(256, 4) void kde_kernel(
    const __hip_bfloat16* __restrict__ Hb, const char* __restrict__ Xbc,
    const float* __restrict__ bwp, float* __restrict__ spart) {
  __shared__ char ldsx[2][CH_BYTES];                 // double-buffered X' chunk [64][256B]
  const int t = threadIdx.x;
  const int lane = t & 63, w = t >> 6;
  const int g = lane >> 4, l15 = lane & 15;
  const int rb = blockIdx.x / NSPLIT, sp = blockIdx.x % NSPLIT;
  const int c0 = (sp * NCH) / NSPLIT;
  const int c1 = ((sp + 1) * NCH) / NSPLIT;
  const float bw = bwp[0];
  float k1 = 1.4426950408889634f / (bw * bw);        // log2(e)/bw^2
  const int rowbase = rb * 128 + w * 32;             // 4 waves x 32 rows = 128 rows/block

  // A fragments: h' rows in registers for the whole kernel (2 rf x 4 ks = 32 VGPR)
  s8v a[2][4];
#pragma unroll
  for (int rf = 0; rf < 2; ++rf)
#pragma unroll
    for (int ks = 0; ks < 4; ++ks) {
      const int row = rowbase + rf * 16 + l15;
      a[rf][ks] = *(const s8v*)(Hb + (size_t)row * KP + ks * 32 + g * 8);
    }
  // Force a[] + k1 materialized NOW: compiler's load-waits land pre-loop, so its
  // in-loop scoreboard never drains our prefetch vmcnt.
#pragma unroll
  for (int rf = 0; rf < 2; ++rf)
#pragma unroll
    for (int ks = 0; ks < 4; ++ks)
      asm volatile("" : "+v"(a[rf][ks]));
  asm volatile("" : "+v"(k1));

  float sacc[8];                                     // per-lane partial sums (rf x reg)
#pragma unroll
  for (int i = 0; i < 8; ++i) sacc[i] = 0.0f;

  // Prologue: prefetch chunks c0, c0+1 (8 vmem ops outstanding)
  stage_tile(ldsx[0], Xbc + (size_t)c0 * CH_BYTES, t);
  if (c0 + 1 < c1) stage_tile(ldsx[1], Xbc + (size_t)(c0 + 1) * CH_BYTES, t);

  const f4v zero4 = {0.0f, 0.0f, 0.0f, 0.0f};
  for (int ch = c0; ch < c1; ++ch) {
    const int cur = (ch - c0) & 1;
    // T4 counted wait: buf[cur]'s 4 loads are the oldest; allow next chunk's 4 to fly.
    if (ch + 1 < c1) {
      asm volatile("s_waitcnt vmcnt(4)" ::: "memory");
    } else {
      asm volatile("s_waitcnt vmcnt(0)" ::: "memory");
    }
    __builtin_amdgcn_s_barrier();                    // all waves' buf[cur] loads done
    const char* lx = ldsx[cur];
#pragma unroll
    for (int cf = 0; cf < 4; ++cf) {                 // 4 col-frags of 16 X-rows
      const int nl = cf * 16 + l15;                  // local X row in chunk
      const int sw = (nl & 7) << 4;                  // read-side XOR swizzle
      const int qb = nl * 256 + g * 16;
      s8v b0 = *(const s8v*)(lx + ((qb) ^ sw));
      s8v b1 = *(const s8v*)(lx + ((qb + 64) ^ sw));
      s8v b2 = *(const s8v*)(lx + ((qb + 128) ^ sw));
      s8v b3 = *(const s8v*)(lx + ((qb + 192) ^ sw));
      __builtin_amdgcn_s_setprio(1);
      f4v acc0 = __builtin_amdgcn_mfma_f32_16x16x32_bf16(a[0][0], b0, zero4, 0, 0, 0);
      acc0 = __builtin_amdgcn_mfma_f32_16x16x32_bf16(a[0][1], b1, acc0, 0, 0, 0);
      acc0 = __builtin_amdgcn_mfma_f32_16x16x32_bf16(a[0][2], b2, acc0, 0, 0, 0);
      acc0 = __builtin_amdgcn_mfma_f32_16x16x32_bf16(a[0][3], b3, acc0, 0, 0, 0);
      f4v acc1 = __builtin_amdgcn_mfma_f32_16x16x32_bf16(a[1][0], b0, zero4, 0, 0, 0);
      acc1 = __builtin_amdgcn_mfma_f32_16x16x32_bf16(a[1][1], b1, acc1, 0, 0, 0);
      acc1 = __builtin_amdgcn_mfma_f32_16x16x32_bf16(a[1][2], b2, acc1, 0, 0, 0);
      acc1 = __builtin_amdgcn_mfma_f32_16x16x32_bf16(a[1][3], b3, acc1, 0, 0, 0);
      __builtin_amdgcn_s_setprio(0);
      // epilogue: acc = -sqdist/2 (aug trick); s += exp2(acc*log2e/bw^2 + 144.27)
#pragma unroll
      for (int reg = 0; reg < 4; ++reg)
        sacc[reg] += fast_exp2(fmaf(acc0[reg], k1, 144.26950408889634f));
#pragma unroll
      for (int reg = 0; reg < 4; ++reg)
        sacc[4 + reg] += fast_exp2(fmaf(acc1[reg], k1, 144.26950408889634f));
    }
    __builtin_amdgcn_s_barrier();                    // all waves done READING buf[cur]
    if (ch + 2 < c1)                                 // refill it two chunks ahead
      stage_tile(ldsx[cur], Xbc + (size_t)(ch + 2) * CH_BYTES, t);
  }

  // butterfly-reduce the 16 column-lanes; rows live at lane-group g, regs rf x reg
#pragma unroll
  for (int i = 0; i < 8; ++i) {
    float v = sacc[i];
    v += __shfl_xor(v, 1, 64);
    v += __shfl_xor(v, 2, 64);
    v += __shfl_xor(v, 4, 64);
    v += __shfl_xor(v, 8, 64);
    sacc[i] = v;
  }
  if (l15 == 0) {
#pragma unroll
    for (int rf = 0; rf < 2; ++rf)
#pragma unroll
      for (int reg = 0; reg < 4; ++reg) {
        const int row = rowbase + rf * 16 + g * 4 + reg;
        spart[sp * B_ROWS + row] = sacc[rf * 4 + reg];
      }
  }
}

// ---------------- Kernel D: combine partials ----------------
__global__ __launch_bounds__(256) void combine_kernel(
    const float* __restrict__ spart, const float* __restrict__ bwp,
    float* __restrict__ out) {
  const int b = blockIdx.x * 256 + threadIdx.x;
  if (b >= B_ROWS) return;
  float s = 0.f;
#pragma unroll
  for (int sp = 0; sp < NSPLIT; ++sp) s += spart[sp * B_ROWS + b];
  const float bw = bwp[0];
  const float LOG2PI = 1.8378770664093453f;
  const float coeff = -logf((float)N_REF) - 0.5f * LOG2PI * (float)D_PCA
                      - logf(bw) * (float)D_PCA;
  out[b] = logf(s) - 100.0f + coeff;   // undo the +100 exp shift
}

// ---------------- Launch ----------------
extern "C" void kernel_launch(void* const* d_in, const int* in_sizes, int n_in,
                              void* d_out, int out_size, void* d_ws, size_t ws_size,
                              hipStream_t stream) {
  const float* x     = (const float*)d_in[0];   // [4096,512]
  const float* W     = (const float*)d_in[1];   // [100,512]
  const float* bvec  = (const float*)d_in[2];   // [100]
  const float* X     = (const float*)d_in[3];   // [50000,100]
  const float* bwp   = (const float*)d_in[4];   // scalar
  float* out = (float*)d_out;

  char* ws = (char*)d_ws;
  __hip_bfloat16* Hb = (__hip_bfloat16*)ws;                       // 4096*128*2   = 1 MiB
  __hip_bfloat16* Xb = (__hip_bfloat16*)(ws + 1048576);           // 50048*128*2  = 12.22 MiB
  __hip_bfloat16* Wb = (__hip_bfloat16*)(ws + 13860864);          // 112*512*2    = 112 KiB
  float* spart       = (float*)(ws + 13975552);                   // 40*4096*4    = 640 KiB

  xprep_kernel<<<dim3(XPREP_BLKS + WPREP_BLKS), dim3(256), 0, stream>>>(X, W, Xb, Wb);
  pca2_kernel<<<dim3(B_ROWS / 16), dim3(256), 0, stream>>>(x, Wb, bvec, Hb);
  kde_kernel<<<dim3((B_ROWS / 128) * NSPLIT), dim3(256), 0, stream>>>(
      Hb, (const char*)Xb, bwp, spart);
  combine_kernel<<<dim3(B_ROWS / 256), dim3(256), 0, stream>>>(spart, bwp, out);
}